// Round 8
// baseline (131.990 us; speedup 1.0000x reference)
//
#include <hip/hip_runtime.h>

typedef _Float16 f16x8 __attribute__((ext_vector_type(8)));
typedef float f32x4 __attribute__((ext_vector_type(4)));
typedef unsigned int u32x4 __attribute__((ext_vector_type(4)));

#define D_DIM 256
#define K_CL  128
#define BM    64
#define KPAD  132          // key row stride (u32)
#define MARGIN 0.1f

__device__ __forceinline__ unsigned pkf16(float a, float b) {
  return __builtin_bit_cast(unsigned, __builtin_amdgcn_cvt_pkrtz(a, b));
}

// 8 waves/block, 64 rows/tile, 512 persistent blocks x 4 tiles (grid-stride).
// fp16 MFMA path; zsq from z*z^T MFMA diagonal (per-row-const error, cancels
// in ranking/gap); csq numpy-pairwise-exact; keys = (sq&~0x7F)|col in LDS
// overlay; reader finds two-smallest + writes s directly. Next tile's z loads
// are PREFETCHED into registers at the top of the MFMA phase (T14 split:
// issue-early / LDS-write-late) to hide HBM latency under compute.
// Ambiguous rows (gap < MARGIN) re-resolved with the numpy-fp32-emulating
// pipeline (verified round 3). launch_bounds(512,4): VGPR<=128, no spill
// (round 6 showed forcing 8 waves/EU -> VGPR=32 -> 136MB scratch disaster).
extern "C" __global__ void __launch_bounds__(512, 4)
k_main(const float* __restrict__ z, const float* __restrict__ cen,
       float* __restrict__ s_out, float* __restrict__ c_out, int ntiles)
{
  __shared__ __align__(16) unsigned char pool[BM * KPAD * 4];  // z16 / keys / refine
  __shared__ float zsq[BM];
  __shared__ float csqnp[K_CL];
  __shared__ unsigned int amb_n;
  __shared__ unsigned char amb_rows[BM];
  __shared__ float zsq_np_sh, sum_sh;
  __shared__ unsigned long long wkey[2];

  const int tid = threadIdx.x;
  const int w   = tid >> 6;
  const int l   = tid & 63;
  const int l15 = l & 15;
  const int g   = l >> 4;

  // ---- csqnp: numpy-exact pairwise sumsq, 8 lanes per cluster, 2 passes.
  {
#pragma clang fp contract(off)
    const int sub = tid & 7;
#pragma unroll
    for (int p = 0; p < 2; ++p) {
      const int c = (tid >> 3) + (p << 6);
      const float* a = cen + (size_t)c * D_DIM;
      float blk[2];
#pragma unroll
      for (int b2 = 0; b2 < 2; ++b2) {
        const float* ab = a + (b2 << 7);
        float x = ab[sub];
        float r = x * x;
        for (int i = 1; i < 16; ++i) { x = ab[(i << 3) + sub]; r = r + x * x; }
        r = r + __shfl_xor(r, 1);   // ((r0+r1)+(r2+r3))+((r4+r5)+(r6+r7))
        r = r + __shfl_xor(r, 2);
        r = r + __shfl_xor(r, 4);
        blk[b2] = r;
      }
      if (sub == 0) csqnp[c] = blk[0] + blk[1];
    }
  }

  // ---- B fragments fp16 in regs: wave w owns clusters w*16..+15.
  // mfma_f32_16x16x32_f16 B layout: lane holds B[k=(l>>4)*8+i][n=l&15].
  f16x8 bf[8];
  {
    const int c = (w << 4) + l15;
    const float* crow = cen + (size_t)c * D_DIM;
#pragma unroll
    for (int k = 0; k < 8; ++k) {
      const int d0 = k * 32 + g * 8;
      const float4 v0 = *(const float4*)(crow + d0);
      const float4 v1 = *(const float4*)(crow + d0 + 4);
      bf[k] = __builtin_bit_cast(f16x8, (u32x4){pkf16(v0.x,v0.y), pkf16(v0.z,v0.w),
                                                pkf16(v1.x,v1.y), pkf16(v1.z,v1.w)});
    }
  }

  // ---- prologue prefetch of first tile's z rows (wave w: rows w*8..w*8+7).
  float4 pf[8];
  int tile = blockIdx.x;
  if (tile < ntiles) {
    const int row0 = tile * BM;
#pragma unroll
    for (int i = 0; i < 8; ++i)
      pf[i] = *(const float4*)(z + (size_t)(row0 + (w << 3) + i) * D_DIM + (l << 2));
  }

  for (; tile < ntiles; tile += gridDim.x) {
    const int row0 = tile * BM;
    if (tid == 0) amb_n = 0;

    // ---- stage z fp16 from prefetched regs (XOR-swizzled 16B chunks).
#pragma unroll
    for (int i = 0; i < 8; ++i) {
      const int r = (w << 3) + i;
      const float4 v = pf[i];
      const int boff = (r << 9) + ((((l >> 1) ^ (r & 31)) << 4) | ((l & 1) << 3));
      *(uint2*)(pool + boff) = make_uint2(pkf16(v.x, v.y), pkf16(v.z, v.w));
    }
    __syncthreads();                                        // bar1

    // ---- issue next tile's loads NOW; they complete under MFMA/keys/reader.
    {
      const int ntile = tile + gridDim.x;
      if (ntile < ntiles) {
        const int nrow0 = ntile * BM;
#pragma unroll
        for (int i = 0; i < 8; ++i)
          pf[i] = *(const float4*)(z + (size_t)(nrow0 + (w << 3) + i) * D_DIM + (l << 2));
      }
    }

    // ---- MFMA; waves 0..3 also accumulate z*z^T for row-tile rt==w.
    f32x4 acc[4];
    f32x4 zz = (f32x4){0.f, 0.f, 0.f, 0.f};
#pragma unroll
    for (int rt = 0; rt < 4; ++rt) acc[rt] = (f32x4){0.f, 0.f, 0.f, 0.f};
#pragma unroll
    for (int k = 0; k < 8; ++k) {
#pragma unroll
      for (int rt = 0; rt < 4; ++rt) {
        const int r = (rt << 4) + l15;   // A: lane holds A[m=l&15][k=(l>>4)*8+i]
        const int boff = (r << 9) + ((((k << 2) + g) ^ (r & 31)) << 4);
        const f16x8 af = *(const f16x8*)(pool + boff);
        acc[rt] = __builtin_amdgcn_mfma_f32_16x16x32_f16(af, bf[k], acc[rt], 0, 0, 0);
        if (rt == w)   // wave-uniform; only waves 0..3 match
          zz = __builtin_amdgcn_mfma_f32_16x16x32_f16(af, af, zz, 0, 0, 0);
      }
    }
    if (w < 4) {       // diag of C: row==col -> l15 == 4g+j, value in reg j
#pragma unroll
      for (int j = 0; j < 4; ++j)
        if (l15 == ((g << 2) + j)) zsq[(w << 4) + l15] = zz[j];
    }
    __syncthreads();                                        // bar2

    // ---- keys. C/D layout: row=(l>>4)*4+reg, col=l&15.
    unsigned* keybuf = (unsigned*)pool;
    const int col = (w << 4) + l15;
    const float cq = csqnp[col];
#pragma unroll
    for (int rt = 0; rt < 4; ++rt) {
#pragma unroll
      for (int j = 0; j < 4; ++j) {
        const int r = (rt << 4) + (g << 2) + j;
        const float sq = fmaxf(fmaf(-2.0f, acc[rt][j], zsq[r] + cq), 0.0f);
        keybuf[r * KPAD + col] = (__float_as_uint(sq) & 0xFFFFFF80u) | (unsigned)col;
      }
    }
    __syncthreads();                                        // bar3

    // ---- reader: 8 threads/row; two-smallest + rowsum + write s + c_out.
    {
      const int rr = tid >> 3;
      const unsigned* kp = keybuf + rr * KPAD + ((tid & 7) << 4);
      unsigned m1 = 0xFFFFFFFFu, m2 = 0xFFFFFFFFu;
      float t[16];
      float sum = 0.f;
#pragma unroll
      for (int q = 0; q < 4; ++q) {
        const u32x4 kv = *(const u32x4*)(kp + (q << 2));
#pragma unroll
        for (int e = 0; e < 4; ++e) {
          const unsigned u = kv[e];
          const unsigned mn = min(m1, u), mx = max(m1, u);
          m1 = mn; m2 = min(m2, mx);
          const float tv = __builtin_amdgcn_rcpf(
              1.0f + __builtin_amdgcn_sqrtf(__uint_as_float(u & 0xFFFFFF80u)));
          t[(q << 2) + e] = tv;
          sum += tv;
        }
      }
#pragma unroll
      for (int m = 1; m <= 4; m <<= 1) {
        const unsigned o1 = __shfl_xor(m1, m);
        const unsigned o2 = __shfl_xor(m2, m);
        sum += __shfl_xor(sum, m);
        const unsigned mn = min(m1, o1), mx = max(m1, o1);
        m1 = mn; m2 = min(mx, min(m2, o2));
      }
      const float rinv = __builtin_amdgcn_rcpf(sum);
      float* srow = s_out + (size_t)(row0 + rr) * K_CL + ((tid & 7) << 4);
#pragma unroll
      for (int q = 0; q < 4; ++q) {
        float4 sv;
        sv.x = t[(q << 2) + 0] * rinv; sv.y = t[(q << 2) + 1] * rinv;
        sv.z = t[(q << 2) + 2] * rinv; sv.w = t[(q << 2) + 3] * rinv;
        *(float4*)(srow + (q << 2)) = sv;
      }
      if ((tid & 7) == 0) {
        c_out[row0 + rr] = (float)(m1 & 0x7Fu);
        const float d1 = __uint_as_float(m1 & 0xFFFFFF80u);
        const float d2 = __uint_as_float(m2 & 0xFFFFFF80u);
        if ((d2 - d1) < MARGIN) {
          const unsigned idx = atomicAdd(&amb_n, 1u);
          amb_rows[idx] = (unsigned char)rr;
        }
      }
    }
    __syncthreads();                                        // bar4

    // ---- numpy-fp32-emulating refinement (parallelized), rare.
    unsigned na = amb_n;
    if (na > BM) na = BM;
    if (na) {
      float* zrow = (float*)pool;           // 256 f (overlays keys)
      float* stmp = (float*)pool + 256;     // 128 f
      for (unsigned e = 0; e < na; ++e) {
        const int r = amb_rows[e];
        __syncthreads();   // previous pool reads complete
        if (tid < 64)
          *(float4*)(zrow + (tid << 2)) =
              *(const float4*)(z + (size_t)(row0 + r) * D_DIM + (tid << 2));
        __syncthreads();
        if (tid < 8) {     // numpy-exact zsq of this row
#pragma clang fp contract(off)
          const int sub = tid;
          float blk[2];
#pragma unroll
          for (int b2 = 0; b2 < 2; ++b2) {
            const float* ab = zrow + (b2 << 7);
            float x = ab[sub];
            float rr2 = x * x;
            for (int i = 1; i < 16; ++i) { x = ab[(i << 3) + sub]; rr2 = rr2 + x * x; }
            rr2 = rr2 + __shfl_xor(rr2, 1);
            rr2 = rr2 + __shfl_xor(rr2, 2);
            rr2 = rr2 + __shfl_xor(rr2, 4);
            blk[b2] = rr2;
          }
          if (sub == 0) zsq_np_sh = blk[0] + blk[1];
        }
        // fp64 dot: 4 threads per cluster (reassociation ~1e-13, far below
        // the 1.7e-4 fp32 s_tmp tie quantum).
        const int c = tid >> 2, part = tid & 3;
        double d = 0.0;
        {
          const float* cp = cen + (size_t)c * D_DIM + (part << 6);
          const float* zp = zrow + (part << 6);
          for (int i = 0; i < 64; ++i)
            d += (double)zp[i] * (double)cp[i];
          d += __shfl_xor(d, 1);
          d += __shfl_xor(d, 2);
        }
        __syncthreads();   // zsq_np_sh visible; zrow reads done
        if (part == 0) {
#pragma clang fp contract(off)
          const float dotf = (float)d;                       // ~sgemm, CR
          const float sq   = (zsq_np_sh + csqnp[c]) - 2.0f * dotf;
          stmp[c] = 1.0f / (1.0f + sqrtf(fmaxf(sq, 0.0f)));  // np pow -1 path
        }
        __syncthreads();
        if (tid < 8) {     // numpy-exact sum of stmp[128]
#pragma clang fp contract(off)
          const int sub = tid;
          float rr2 = stmp[sub];
          for (int i = 1; i < 16; ++i) rr2 = rr2 + stmp[(i << 3) + sub];
          rr2 = rr2 + __shfl_xor(rr2, 1);
          rr2 = rr2 + __shfl_xor(rr2, 2);
          rr2 = rr2 + __shfl_xor(rr2, 4);
          if (sub == 0) sum_sh = rr2;
        }
        __syncthreads();
        if (tid < 128) {   // parallel divide + first-index-wins argmax
          const float s = stmp[tid] / sum_sh;                // IEEE div, like np
          unsigned long long key =
              ((unsigned long long)(0x7FFFFFFFu - __float_as_uint(s)) << 32) |
              (unsigned)tid;
#pragma unroll
          for (int m = 1; m < 64; m <<= 1) {
            const unsigned long long o = __shfl_xor(key, m);
            key = o < key ? o : key;
          }
          if ((tid & 63) == 0) wkey[tid >> 6] = key;
        }
        __syncthreads();
        if (tid == 0) {
          const unsigned long long k2 = wkey[0] < wkey[1] ? wkey[0] : wkey[1];
          c_out[row0 + r] = (float)(unsigned)(k2 & 0x7Fu);
        }
      }
    }
  }
}

extern "C" void kernel_launch(void* const* d_in, const int* in_sizes, int n_in,
                              void* d_out, int out_size, void* d_ws, size_t ws_size,
                              hipStream_t stream) {
  const float* z   = (const float*)d_in[0];
  const float* cen = (const float*)d_in[1];
  const int M = in_sizes[0] / D_DIM;   // 131072
  float* s_out = (float*)d_out;
  float* c_out = s_out + (size_t)M * K_CL;
  const int ntiles = M / BM;           // 2048
  // 512 persistent blocks (2/CU resident at VGPR~110), 4 tiles each; every
  // tile after the first is register-prefetched.
  const int nblk = ntiles < 512 ? ntiles : 512;

  hipLaunchKernelGGL(k_main, dim3(nblk), dim3(512), 0, stream,
                     z, cen, s_out, c_out, ntiles);
}

// Round 11
// 125.918 us; speedup vs baseline: 1.0482x; 1.0482x over previous
//
#include <hip/hip_runtime.h>

typedef _Float16 f16x8 __attribute__((ext_vector_type(8)));
typedef float f32x4 __attribute__((ext_vector_type(4)));
typedef unsigned int u32x4 __attribute__((ext_vector_type(4)));

#define D_DIM 256
#define K_CL  128
#define BM    64
#define KPAD  132          // key row stride (u32)
#define MARGIN 0.1f       // 0.05 escaped a flip in r10 (sigma_gap ~2e-2); 0.1 passed r5/r7/r8

__device__ __forceinline__ unsigned pkf16(float a, float b) {
  return __builtin_bit_cast(unsigned, __builtin_amdgcn_cvt_pkrtz(a, b));
}

// 8 waves/block, 64 rows/tile, 512 persistent blocks x 4 tiles (grid-stride).
// fp16 MFMA path; zsq from z*z^T MFMA diagonal (per-row-const error, cancels
// in ranking/gap); csq numpy-pairwise-exact (float4-vectorized, tree order
// preserved); keys = (sq&~0x7F)|col in LDS overlay; reader finds two-smallest
// + writes s directly (nontemporal — s is never re-read, keep z in L3).
// Next tile's z rows prefetched into registers under the MFMA phase.
// Ambiguous rows (gap < MARGIN) re-resolved with the numpy-fp32-emulating
// pipeline (verified round 3). launch_bounds: NO min-occupancy arg — both
// (512,8) [r6] and (512,4) [r8] forced VGPR under live-state and spilled.
extern "C" __global__ void __launch_bounds__(512)
k_main(const float* __restrict__ z, const float* __restrict__ cen,
       float* __restrict__ s_out, float* __restrict__ c_out, int ntiles)
{
  __shared__ __align__(16) unsigned char pool[BM * KPAD * 4];  // z16 / keys / refine
  __shared__ float zsq[BM];
  __shared__ float csqnp[K_CL];
  __shared__ unsigned int amb_n;
  __shared__ unsigned char amb_rows[BM];
  __shared__ float zsq_np_sh, sum_sh;
  __shared__ unsigned long long wkey[2];

  const int tid = threadIdx.x;
  const int w   = tid >> 6;
  const int l   = tid & 63;
  const int l15 = l & 15;
  const int g   = l >> 4;

  // ---- csqnp: numpy-exact pairwise sumsq, float4 loads, 2 lanes/cluster.
  // np 8-accumulator pattern: lane s holds r[4s..4s+3] as v[0..3];
  // in-lane (v0+v1)+(v2+v3); cross-lane s0+s1 reproduces
  // ((r0+r1)+(r2+r3))+((r4+r5)+(r6+r7)); blocks combined blk0+blk1.
  {
#pragma clang fp contract(off)
    float blk0 = 0.f, blk1 = 0.f;
    const int c = tid >> 1, s = tid & 1;
    if (tid < 256) {
      const float* a = cen + (size_t)c * D_DIM + (s << 2);
#pragma unroll
      for (int b2 = 0; b2 < 2; ++b2) {
        const float* ab = a + (b2 << 7);
        const float4 v0 = *(const float4*)(ab);
        float v[4] = {v0.x * v0.x, v0.y * v0.y, v0.z * v0.z, v0.w * v0.w};
        for (int i = 1; i < 16; ++i) {
          const float4 vi = *(const float4*)(ab + (i << 3));
          v[0] = v[0] + vi.x * vi.x; v[1] = v[1] + vi.y * vi.y;
          v[2] = v[2] + vi.z * vi.z; v[3] = v[3] + vi.w * vi.w;
        }
        const float part = (v[0] + v[1]) + (v[2] + v[3]);
        if (b2 == 0) blk0 = part; else blk1 = part;
      }
    }
    const float o0 = __shfl_xor(blk0, 1);   // partner lane's 4-acc partial
    const float o1 = __shfl_xor(blk1, 1);
    if (tid < 256 && s == 0)
      csqnp[c] = (blk0 + o0) + (blk1 + o1);
  }

  // ---- B fragments fp16 in regs: wave w owns clusters w*16..+15.
  // mfma_f32_16x16x32_f16 B layout: lane holds B[k=(l>>4)*8+i][n=l&15].
  f16x8 bf[8];
  {
    const int c = (w << 4) + l15;
    const float* crow = cen + (size_t)c * D_DIM;
#pragma unroll
    for (int k = 0; k < 8; ++k) {
      const int d0 = k * 32 + g * 8;
      const float4 v0 = *(const float4*)(crow + d0);
      const float4 v1 = *(const float4*)(crow + d0 + 4);
      bf[k] = __builtin_bit_cast(f16x8, (u32x4){pkf16(v0.x,v0.y), pkf16(v0.z,v0.w),
                                                pkf16(v1.x,v1.y), pkf16(v1.z,v1.w)});
    }
  }

  // ---- prologue prefetch of first tile's z rows (wave w: rows w*8..w*8+7).
  float4 pf[8];
  int tile = blockIdx.x;
  if (tile < ntiles) {
    const int row0 = tile * BM;
#pragma unroll
    for (int i = 0; i < 8; ++i)
      pf[i] = *(const float4*)(z + (size_t)(row0 + (w << 3) + i) * D_DIM + (l << 2));
  }

  for (; tile < ntiles; tile += gridDim.x) {
    const int row0 = tile * BM;
    if (tid == 0) amb_n = 0;

    // ---- stage z fp16 from prefetched regs (XOR-swizzled 16B chunks).
#pragma unroll
    for (int i = 0; i < 8; ++i) {
      const int r = (w << 3) + i;
      const float4 v = pf[i];
      const int boff = (r << 9) + ((((l >> 1) ^ (r & 31)) << 4) | ((l & 1) << 3));
      *(uint2*)(pool + boff) = make_uint2(pkf16(v.x, v.y), pkf16(v.z, v.w));
    }
    __syncthreads();                                        // bar1

    // ---- issue next tile's loads NOW; they complete under MFMA/keys/reader.
    {
      const int ntile = tile + gridDim.x;
      if (ntile < ntiles) {
        const int nrow0 = ntile * BM;
#pragma unroll
        for (int i = 0; i < 8; ++i)
          pf[i] = *(const float4*)(z + (size_t)(nrow0 + (w << 3) + i) * D_DIM + (l << 2));
      }
    }

    // ---- MFMA; waves 0..3 also accumulate z*z^T for row-tile rt==w.
    f32x4 acc[4];
    f32x4 zz = (f32x4){0.f, 0.f, 0.f, 0.f};
#pragma unroll
    for (int rt = 0; rt < 4; ++rt) acc[rt] = (f32x4){0.f, 0.f, 0.f, 0.f};
#pragma unroll
    for (int k = 0; k < 8; ++k) {
#pragma unroll
      for (int rt = 0; rt < 4; ++rt) {
        const int r = (rt << 4) + l15;   // A: lane holds A[m=l&15][k=(l>>4)*8+i]
        const int boff = (r << 9) + ((((k << 2) + g) ^ (r & 31)) << 4);
        const f16x8 af = *(const f16x8*)(pool + boff);
        acc[rt] = __builtin_amdgcn_mfma_f32_16x16x32_f16(af, bf[k], acc[rt], 0, 0, 0);
        if (rt == w)   // wave-uniform; only waves 0..3 match
          zz = __builtin_amdgcn_mfma_f32_16x16x32_f16(af, af, zz, 0, 0, 0);
      }
    }
    if (w < 4) {       // diag of C: row==col -> l15 == 4g+j, value in reg j
#pragma unroll
      for (int j = 0; j < 4; ++j)
        if (l15 == ((g << 2) + j)) zsq[(w << 4) + l15] = zz[j];
    }
    __syncthreads();                                        // bar2

    // ---- keys. C/D layout: row=(l>>4)*4+reg, col=l&15.
    unsigned* keybuf = (unsigned*)pool;
    const int col = (w << 4) + l15;
    const float cq = csqnp[col];
#pragma unroll
    for (int rt = 0; rt < 4; ++rt) {
#pragma unroll
      for (int j = 0; j < 4; ++j) {
        const int r = (rt << 4) + (g << 2) + j;
        const float sq = fmaxf(fmaf(-2.0f, acc[rt][j], zsq[r] + cq), 0.0f);
        keybuf[r * KPAD + col] = (__float_as_uint(sq) & 0xFFFFFF80u) | (unsigned)col;
      }
    }
    __syncthreads();                                        // bar3

    // ---- reader: 8 threads/row; two-smallest + rowsum + write s + c_out.
    {
      const int rr = tid >> 3;
      const unsigned* kp = keybuf + rr * KPAD + ((tid & 7) << 4);
      unsigned m1 = 0xFFFFFFFFu, m2 = 0xFFFFFFFFu;
      float t[16];
      float sum = 0.f;
#pragma unroll
      for (int q = 0; q < 4; ++q) {
        const u32x4 kv = *(const u32x4*)(kp + (q << 2));
#pragma unroll
        for (int e = 0; e < 4; ++e) {
          const unsigned u = kv[e];
          const unsigned mn = min(m1, u), mx = max(m1, u);
          m1 = mn; m2 = min(m2, mx);
          const float tv = __builtin_amdgcn_rcpf(
              1.0f + __builtin_amdgcn_sqrtf(__uint_as_float(u & 0xFFFFFF80u)));
          t[(q << 2) + e] = tv;
          sum += tv;
        }
      }
#pragma unroll
      for (int m = 1; m <= 4; m <<= 1) {
        const unsigned o1 = __shfl_xor(m1, m);
        const unsigned o2 = __shfl_xor(m2, m);
        sum += __shfl_xor(sum, m);
        const unsigned mn = min(m1, o1), mx = max(m1, o1);
        m1 = mn; m2 = min(mx, min(m2, o2));
      }
      const float rinv = __builtin_amdgcn_rcpf(sum);
      float* srow = s_out + (size_t)(row0 + rr) * K_CL + ((tid & 7) << 4);
#pragma unroll
      for (int q = 0; q < 4; ++q) {
        f32x4 sv;
        sv[0] = t[(q << 2) + 0] * rinv; sv[1] = t[(q << 2) + 1] * rinv;
        sv[2] = t[(q << 2) + 2] * rinv; sv[3] = t[(q << 2) + 3] * rinv;
        __builtin_nontemporal_store(sv, (f32x4*)(srow + (q << 2)));
      }
      if ((tid & 7) == 0) {
        c_out[row0 + rr] = (float)(m1 & 0x7Fu);
        const float d1 = __uint_as_float(m1 & 0xFFFFFF80u);
        const float d2 = __uint_as_float(m2 & 0xFFFFFF80u);
        if ((d2 - d1) < MARGIN) {
          const unsigned idx = atomicAdd(&amb_n, 1u);
          amb_rows[idx] = (unsigned char)rr;
        }
      }
    }
    __syncthreads();                                        // bar4

    // ---- numpy-fp32-emulating refinement (parallelized), rare.
    unsigned na = amb_n;
    if (na > BM) na = BM;
    if (na) {
      float* zrow = (float*)pool;           // 256 f (overlays keys)
      float* stmp = (float*)pool + 256;     // 128 f
      for (unsigned e = 0; e < na; ++e) {
        const int r = amb_rows[e];
        __syncthreads();   // previous pool reads complete
        if (tid < 64)
          *(float4*)(zrow + (tid << 2)) =
              *(const float4*)(z + (size_t)(row0 + r) * D_DIM + (tid << 2));
        __syncthreads();
        if (tid < 8) {     // numpy-exact zsq of this row
#pragma clang fp contract(off)
          const int sub = tid;
          float blk[2];
#pragma unroll
          for (int b2 = 0; b2 < 2; ++b2) {
            const float* ab = zrow + (b2 << 7);
            float x = ab[sub];
            float rr2 = x * x;
            for (int i = 1; i < 16; ++i) { x = ab[(i << 3) + sub]; rr2 = rr2 + x * x; }
            rr2 = rr2 + __shfl_xor(rr2, 1);
            rr2 = rr2 + __shfl_xor(rr2, 2);
            rr2 = rr2 + __shfl_xor(rr2, 4);
            blk[b2] = rr2;
          }
          if (sub == 0) zsq_np_sh = blk[0] + blk[1];
        }
        // fp64 dot: 4 threads per cluster (reassociation ~1e-13, far below
        // the 1.7e-4 fp32 s_tmp tie quantum).
        const int c = tid >> 2, part = tid & 3;
        double d = 0.0;
        {
          const float* cp = cen + (size_t)c * D_DIM + (part << 6);
          const float* zp = zrow + (part << 6);
          for (int i = 0; i < 64; ++i)
            d += (double)zp[i] * (double)cp[i];
          d += __shfl_xor(d, 1);
          d += __shfl_xor(d, 2);
        }
        __syncthreads();   // zsq_np_sh visible; zrow reads done
        if (part == 0) {
#pragma clang fp contract(off)
          const float dotf = (float)d;                       // ~sgemm, CR
          const float sq   = (zsq_np_sh + csqnp[c]) - 2.0f * dotf;
          stmp[c] = 1.0f / (1.0f + sqrtf(fmaxf(sq, 0.0f)));  // np pow -1 path
        }
        __syncthreads();
        if (tid < 8) {     // numpy-exact sum of stmp[128]
#pragma clang fp contract(off)
          const int sub = tid;
          float rr2 = stmp[sub];
          for (int i = 1; i < 16; ++i) rr2 = rr2 + stmp[(i << 3) + sub];
          rr2 = rr2 + __shfl_xor(rr2, 1);
          rr2 = rr2 + __shfl_xor(rr2, 2);
          rr2 = rr2 + __shfl_xor(rr2, 4);
          if (sub == 0) sum_sh = rr2;
        }
        __syncthreads();
        if (tid < 128) {   // parallel divide + first-index-wins argmax
          const float s = stmp[tid] / sum_sh;                // IEEE div, like np
          unsigned long long key =
              ((unsigned long long)(0x7FFFFFFFu - __float_as_uint(s)) << 32) |
              (unsigned)tid;
#pragma unroll
          for (int m = 1; m < 64; m <<= 1) {
            const unsigned long long o = __shfl_xor(key, m);
            key = o < key ? o : key;
          }
          if ((tid & 63) == 0) wkey[tid >> 6] = key;
        }
        __syncthreads();
        if (tid == 0) {
          const unsigned long long k2 = wkey[0] < wkey[1] ? wkey[0] : wkey[1];
          c_out[row0 + r] = (float)(unsigned)(k2 & 0x7Fu);
        }
      }
    }
  }
}

extern "C" void kernel_launch(void* const* d_in, const int* in_sizes, int n_in,
                              void* d_out, int out_size, void* d_ws, size_t ws_size,
                              hipStream_t stream) {
  const float* z   = (const float*)d_in[0];
  const float* cen = (const float*)d_in[1];
  const int M = in_sizes[0] / D_DIM;   // 131072
  float* s_out = (float*)d_out;
  float* c_out = s_out + (size_t)M * K_CL;
  const int ntiles = M / BM;           // 2048
  const int nblk = ntiles < 512 ? ntiles : 512;   // persistent, 4 tiles each

  hipLaunchKernelGGL(k_main, dim3(nblk), dim3(512), 0, stream,
                     z, cen, s_out, c_out, ntiles);
}

// Round 12
// 104.356 us; speedup vs baseline: 1.2648x; 1.2066x over previous
//
#include <hip/hip_runtime.h>

typedef _Float16 f16x8 __attribute__((ext_vector_type(8)));
typedef float f32x4 __attribute__((ext_vector_type(4)));
typedef unsigned int u32x4 __attribute__((ext_vector_type(4)));

#define D_DIM 256
#define K_CL  128
#define BM    32           // rows per tile (4-wave blocks)
#define KPAD  132          // key row stride (u32)
#define MARGIN 0.1f        // 0.05 escaped a flip in r10; 0.1 passed r5/r7/r8/r11

__device__ __forceinline__ unsigned pkf16(float a, float b) {
  return __builtin_bit_cast(unsigned, __builtin_amdgcn_cvt_pkrtz(a, b));
}

// 4 waves/block, 32 rows/tile, 1024 persistent blocks x 4 tiles. Wave w owns
// clusters w*32..w*32+31 (bf[2][8] fp16 fragments in regs). fp16 MFMA; zsq
// from z*z^T MFMA diagonal (per-row-const error, cancels in ranking/gap);
// csq numpy-pairwise-exact; keys=(sq&~0x7F)|col in LDS overlay; reader does
// two-smallest + rowsum, then re-reads keys to write s (no t[] cache: VGPR).
// Ambiguous rows (gap<MARGIN) re-resolved with the numpy-fp32-emulating
// pipeline (verified r3). Rationale this round: 4 independent 4-wave barrier
// domains per CU (vs 2x8) to break the all-waves-at-same-barrier stall; plain
// (non-NT) s stores — NT caused 2.65x write amplification in r11.
extern "C" __global__ void __launch_bounds__(256)
k_main(const float* __restrict__ z, const float* __restrict__ cen,
       float* __restrict__ s_out, float* __restrict__ c_out, int ntiles)
{
  __shared__ __align__(16) unsigned char pool[BM * KPAD * 4];  // z16 / keys / refine
  __shared__ float zsq[BM];
  __shared__ float csqnp[K_CL];
  __shared__ unsigned int amb_n;
  __shared__ unsigned char amb_rows[BM];
  __shared__ float zsq_np_sh, sum_sh;
  __shared__ unsigned long long wkey[2];

  const int tid = threadIdx.x;
  const int w   = tid >> 6;      // wave 0..3
  const int l   = tid & 63;
  const int l15 = l & 15;
  const int g   = l >> 4;

  // ---- csqnp: numpy-exact pairwise sumsq, float4 loads, 2 lanes/cluster.
  // lane sub holds np accumulators r[4*sub..4*sub+3]; in-lane (v0+v1)+(v2+v3);
  // cross-lane sub0+sub1 == ((r0+r1)+(r2+r3))+((r4+r5)+(r6+r7)); blk0+blk1.
  {
#pragma clang fp contract(off)
    float blk0 = 0.f, blk1 = 0.f;
    const int c = tid >> 1, sub = tid & 1;
    const float* a = cen + (size_t)c * D_DIM + (sub << 2);
#pragma unroll
    for (int b2 = 0; b2 < 2; ++b2) {
      const float* ab = a + (b2 << 7);
      const float4 v0 = *(const float4*)(ab);
      float v[4] = {v0.x * v0.x, v0.y * v0.y, v0.z * v0.z, v0.w * v0.w};
      for (int i = 1; i < 16; ++i) {
        const float4 vi = *(const float4*)(ab + (i << 3));
        v[0] = v[0] + vi.x * vi.x; v[1] = v[1] + vi.y * vi.y;
        v[2] = v[2] + vi.z * vi.z; v[3] = v[3] + vi.w * vi.w;
      }
      const float part = (v[0] + v[1]) + (v[2] + v[3]);
      if (b2 == 0) blk0 = part; else blk1 = part;
    }
    const float o0 = __shfl_xor(blk0, 1);
    const float o1 = __shfl_xor(blk1, 1);
    if (sub == 0) csqnp[c] = (blk0 + o0) + (blk1 + o1);
  }

  // ---- B fragments fp16 in regs: wave w owns clusters w*32..+31 (2 ct).
  // mfma_f32_16x16x32_f16 B layout: lane holds B[k=(l>>4)*8+i][n=l&15].
  f16x8 bf[2][8];
#pragma unroll
  for (int ct = 0; ct < 2; ++ct) {
    const int c = (w << 5) + (ct << 4) + l15;
    const float* crow = cen + (size_t)c * D_DIM;
#pragma unroll
    for (int k = 0; k < 8; ++k) {
      const int d0 = k * 32 + g * 8;
      const float4 v0 = *(const float4*)(crow + d0);
      const float4 v1 = *(const float4*)(crow + d0 + 4);
      bf[ct][k] = __builtin_bit_cast(f16x8,
          (u32x4){pkf16(v0.x,v0.y), pkf16(v0.z,v0.w),
                  pkf16(v1.x,v1.y), pkf16(v1.z,v1.w)});
    }
  }

  for (int tile = blockIdx.x; tile < ntiles; tile += gridDim.x) {
    const int row0 = tile * BM;
    if (tid == 0) amb_n = 0;

    // ---- stage z fp16 (XOR-swizzled 16B chunks): wave w rows w*8..w*8+7.
#pragma unroll
    for (int i = 0; i < 8; ++i) {
      const int r = (w << 3) + i;
      const float4 v = *(const float4*)(z + (size_t)(row0 + r) * D_DIM + (l << 2));
      const int boff = (r << 9) + ((((l >> 1) ^ (r & 31)) << 4) | ((l & 1) << 3));
      *(uint2*)(pool + boff) = make_uint2(pkf16(v.x, v.y), pkf16(v.z, v.w));
    }
    __syncthreads();                                        // bar1

    // ---- MFMA; waves 0..1 also accumulate z*z^T for row-tile rt==w.
    f32x4 acc[2][2];
    f32x4 zz = (f32x4){0.f, 0.f, 0.f, 0.f};
#pragma unroll
    for (int rt = 0; rt < 2; ++rt)
#pragma unroll
      for (int ct = 0; ct < 2; ++ct) acc[rt][ct] = (f32x4){0.f, 0.f, 0.f, 0.f};
#pragma unroll
    for (int k = 0; k < 8; ++k) {
#pragma unroll
      for (int rt = 0; rt < 2; ++rt) {
        const int r = (rt << 4) + l15;   // A: lane holds A[m=l&15][k=(l>>4)*8+i]
        const int boff = (r << 9) + ((((k << 2) + g) ^ (r & 31)) << 4);
        const f16x8 af = *(const f16x8*)(pool + boff);
        acc[rt][0] = __builtin_amdgcn_mfma_f32_16x16x32_f16(af, bf[0][k], acc[rt][0], 0, 0, 0);
        acc[rt][1] = __builtin_amdgcn_mfma_f32_16x16x32_f16(af, bf[1][k], acc[rt][1], 0, 0, 0);
        if (rt == w)   // wave-uniform; true only for waves 0..1
          zz = __builtin_amdgcn_mfma_f32_16x16x32_f16(af, af, zz, 0, 0, 0);
      }
    }
    if (w < 2) {       // diag of C: row==col -> l15 == 4g+j, value in reg j
#pragma unroll
      for (int j = 0; j < 4; ++j)
        if (l15 == ((g << 2) + j)) zsq[(w << 4) + l15] = zz[j];
    }
    __syncthreads();                                        // bar2

    // ---- keys. C/D layout: row=(l>>4)*4+reg, col=l&15.
    unsigned* keybuf = (unsigned*)pool;
#pragma unroll
    for (int rt = 0; rt < 2; ++rt) {
#pragma unroll
      for (int ct = 0; ct < 2; ++ct) {
        const int col = (w << 5) + (ct << 4) + l15;
        const float cq = csqnp[col];
#pragma unroll
        for (int j = 0; j < 4; ++j) {
          const int r = (rt << 4) + (g << 2) + j;
          const float sq = fmaxf(fmaf(-2.0f, acc[rt][ct][j], zsq[r] + cq), 0.0f);
          keybuf[r * KPAD + col] = (__float_as_uint(sq) & 0xFFFFFF80u) | (unsigned)col;
        }
      }
    }
    __syncthreads();                                        // bar3

    // ---- reader: 8 threads/row; pass1 two-smallest+rowsum, pass2 write s.
    {
      const int rr = tid >> 3;
      const unsigned* kp = keybuf + rr * KPAD + ((tid & 7) << 4);
      unsigned m1 = 0xFFFFFFFFu, m2 = 0xFFFFFFFFu;
      float sum = 0.f;
#pragma unroll
      for (int q = 0; q < 4; ++q) {
        const u32x4 kv = *(const u32x4*)(kp + (q << 2));
#pragma unroll
        for (int e = 0; e < 4; ++e) {
          const unsigned u = kv[e];
          const unsigned mn = min(m1, u), mx = max(m1, u);
          m1 = mn; m2 = min(m2, mx);
          sum += __builtin_amdgcn_rcpf(
              1.0f + __builtin_amdgcn_sqrtf(__uint_as_float(u & 0xFFFFFF80u)));
        }
      }
#pragma unroll
      for (int m = 1; m <= 4; m <<= 1) {
        const unsigned o1 = __shfl_xor(m1, m);
        const unsigned o2 = __shfl_xor(m2, m);
        sum += __shfl_xor(sum, m);
        const unsigned mn = min(m1, o1), mx = max(m1, o1);
        m1 = mn; m2 = min(mx, min(m2, o2));
      }
      const float rinv = __builtin_amdgcn_rcpf(sum);
      float* srow = s_out + (size_t)(row0 + rr) * K_CL + ((tid & 7) << 4);
#pragma unroll
      for (int q = 0; q < 4; ++q) {       // pass 2: re-read keys, write s
        const u32x4 kv = *(const u32x4*)(kp + (q << 2));
        f32x4 sv;
#pragma unroll
        for (int e = 0; e < 4; ++e)
          sv[e] = __builtin_amdgcn_rcpf(
              1.0f + __builtin_amdgcn_sqrtf(__uint_as_float(kv[e] & 0xFFFFFF80u))) * rinv;
        *(f32x4*)(srow + (q << 2)) = sv;
      }
      if ((tid & 7) == 0) {
        c_out[row0 + rr] = (float)(m1 & 0x7Fu);
        const float d1 = __uint_as_float(m1 & 0xFFFFFF80u);
        const float d2 = __uint_as_float(m2 & 0xFFFFFF80u);
        if ((d2 - d1) < MARGIN) {
          const unsigned idx = atomicAdd(&amb_n, 1u);
          amb_rows[idx] = (unsigned char)rr;
        }
      }
    }
    __syncthreads();                                        // bar4

    // ---- numpy-fp32-emulating refinement (parallelized), rare.
    unsigned na = amb_n;
    if (na > BM) na = BM;
    if (na) {
      float* zrow = (float*)pool;           // 256 f (overlays keys)
      float* stmp = (float*)pool + 256;     // 128 f
      for (unsigned e = 0; e < na; ++e) {
        const int r = amb_rows[e];
        __syncthreads();   // previous pool reads complete
        if (tid < 64)
          *(float4*)(zrow + (tid << 2)) =
              *(const float4*)(z + (size_t)(row0 + r) * D_DIM + (tid << 2));
        __syncthreads();
        if (tid < 8) {     // numpy-exact zsq of this row
#pragma clang fp contract(off)
          const int sub = tid;
          float blk[2];
#pragma unroll
          for (int b2 = 0; b2 < 2; ++b2) {
            const float* ab = zrow + (b2 << 7);
            float x = ab[sub];
            float rr2 = x * x;
            for (int i = 1; i < 16; ++i) { x = ab[(i << 3) + sub]; rr2 = rr2 + x * x; }
            rr2 = rr2 + __shfl_xor(rr2, 1);
            rr2 = rr2 + __shfl_xor(rr2, 2);
            rr2 = rr2 + __shfl_xor(rr2, 4);
            blk[b2] = rr2;
          }
          if (sub == 0) zsq_np_sh = blk[0] + blk[1];
        }
        // fp64 dot: 2 threads per cluster, 128 dims each (reassoc ~1e-13,
        // far below the 1.7e-4 fp32 s_tmp tie quantum).
        const int c = tid >> 1, part = tid & 1;
        double d = 0.0;
        {
          const float* cp = cen + (size_t)c * D_DIM + (part << 7);
          const float* zp = zrow + (part << 7);
          for (int i = 0; i < 128; ++i)
            d += (double)zp[i] * (double)cp[i];
          d += __shfl_xor(d, 1);
        }
        __syncthreads();   // zsq_np_sh visible; zrow reads done
        if (part == 0) {
#pragma clang fp contract(off)
          const float dotf = (float)d;                       // ~sgemm, CR
          const float sq   = (zsq_np_sh + csqnp[c]) - 2.0f * dotf;
          stmp[c] = 1.0f / (1.0f + sqrtf(fmaxf(sq, 0.0f)));  // np pow -1 path
        }
        __syncthreads();
        if (tid < 8) {     // numpy-exact sum of stmp[128]
#pragma clang fp contract(off)
          const int sub = tid;
          float rr2 = stmp[sub];
          for (int i = 1; i < 16; ++i) rr2 = rr2 + stmp[(i << 3) + sub];
          rr2 = rr2 + __shfl_xor(rr2, 1);
          rr2 = rr2 + __shfl_xor(rr2, 2);
          rr2 = rr2 + __shfl_xor(rr2, 4);
          if (sub == 0) sum_sh = rr2;
        }
        __syncthreads();
        if (tid < 128) {   // parallel divide + first-index-wins argmax
          const float sv = stmp[tid] / sum_sh;               // IEEE div, like np
          unsigned long long key =
              ((unsigned long long)(0x7FFFFFFFu - __float_as_uint(sv)) << 32) |
              (unsigned)tid;
#pragma unroll
          for (int m = 1; m < 64; m <<= 1) {
            const unsigned long long o = __shfl_xor(key, m);
            key = o < key ? o : key;
          }
          if ((tid & 63) == 0) wkey[tid >> 6] = key;
        }
        __syncthreads();
        if (tid == 0) {
          const unsigned long long k2 = wkey[0] < wkey[1] ? wkey[0] : wkey[1];
          c_out[row0 + r] = (float)(unsigned)(k2 & 0x7Fu);
        }
      }
    }
  }
}

extern "C" void kernel_launch(void* const* d_in, const int* in_sizes, int n_in,
                              void* d_out, int out_size, void* d_ws, size_t ws_size,
                              hipStream_t stream) {
  const float* z   = (const float*)d_in[0];
  const float* cen = (const float*)d_in[1];
  const int M = in_sizes[0] / D_DIM;   // 131072
  float* s_out = (float*)d_out;
  float* c_out = s_out + (size_t)M * K_CL;
  const int ntiles = M / BM;           // 4096
  const int nblk = ntiles < 1024 ? ntiles : 1024;  // 4 blocks/CU, 4 tiles each

  hipLaunchKernelGGL(k_main, dim3(nblk), dim3(256), 0, stream,
                     z, cen, s_out, c_out, ntiles);
}

// Round 13
// 84.930 us; speedup vs baseline: 1.5541x; 1.2287x over previous
//
#include <hip/hip_runtime.h>

typedef _Float16 f16x8 __attribute__((ext_vector_type(8)));
typedef float f32x4 __attribute__((ext_vector_type(4)));
typedef unsigned int u32x4 __attribute__((ext_vector_type(4)));

#define D_DIM 256
#define K_CL  128
#define WR    16           // rows per wave-tile
#define MARGIN 0.1f        // verified r5/r7/r8/r11/r12 (0.05 escaped a flip in r10)

__device__ __forceinline__ unsigned pkf16(float a, float b) {
  return __builtin_bit_cast(unsigned, __builtin_amdgcn_cvt_pkrtz(a, b));
}

// Barrier-free steady state: B fp16 MFMA fragments for ALL 128 clusters in
// LDS (64KB, fragment-linear, written once; the ONLY __syncthreads). Each
// wave independently processes 16-row tiles: z -> A-frags direct from global,
// fp32 zsq (per-row-const choice cancels in ranking), 64 MFMA, in-register
// two-smallest+sum (in-lane over 8 ct, then 4-step shfl butterfly over the
// 16-lane group), s written from quantized keys. Ambiguous rows (gap<MARGIN)
// refined WAVE-LOCALLY with the numpy-fp32-emulating pipeline (ops bit-
// identical to the r3-verified version; lgkmcnt-only sync, wave lockstep).
extern "C" __global__ void __launch_bounds__(512)
k_main(const float* __restrict__ z, const float* __restrict__ cen,
       float* __restrict__ s_out, float* __restrict__ c_out, int ntiles)
{
  __shared__ __align__(16) unsigned int Bf[16384];   // 64KB: chunk(ct,k): 1KB, lane*16B
  __shared__ float csqnp[K_CL];
  __shared__ __align__(16) float zrow_s[8][D_DIM];   // per-wave refine scratch
  __shared__ float stmp_s[8][K_CL];

  const int tid = threadIdx.x;
  const int w   = tid >> 6;
  const int l   = tid & 63;
  const int l15 = l & 15;
  const int g   = l >> 4;

  // ---- csqnp: numpy-exact pairwise sumsq (verified r12 pattern), tid<256.
  if (tid < 256) {
#pragma clang fp contract(off)
    float blk0 = 0.f, blk1 = 0.f;
    const int c = tid >> 1, sub = tid & 1;
    const float* a = cen + (size_t)c * D_DIM + (sub << 2);
#pragma unroll
    for (int b2 = 0; b2 < 2; ++b2) {
      const float* ab = a + (b2 << 7);
      const float4 v0 = *(const float4*)(ab);
      float v[4] = {v0.x * v0.x, v0.y * v0.y, v0.z * v0.z, v0.w * v0.w};
      for (int i = 1; i < 16; ++i) {
        const float4 vi = *(const float4*)(ab + (i << 3));
        v[0] = v[0] + vi.x * vi.x; v[1] = v[1] + vi.y * vi.y;
        v[2] = v[2] + vi.z * vi.z; v[3] = v[3] + vi.w * vi.w;
      }
      const float part = (v[0] + v[1]) + (v[2] + v[3]);
      if (b2 == 0) blk0 = part; else blk1 = part;
    }
    const float o0 = __shfl_xor(blk0, 1);
    const float o1 = __shfl_xor(blk1, 1);
    if (sub == 0) csqnp[c] = (blk0 + o0) + (blk1 + o1);
  }

  // ---- B fragments -> LDS, fragment-linear. chunk ch=ct*8+k: lane l holds
  // B[k=(l>>4)*8+i][col=ct*16+(l&15)] = cen[col][k*32+(l>>4)*8+i], 8 fp16.
#pragma unroll
  for (int j = 0; j < 8; ++j) {
    const int ch = w + (j << 3);
    const int ct = ch >> 3, k = ch & 7;
    const float* cp = cen + (size_t)((ct << 4) + l15) * D_DIM + (k << 5) + (g << 3);
    const float4 v0 = *(const float4*)(cp);
    const float4 v1 = *(const float4*)(cp + 4);
    *(u32x4*)((char*)Bf + (ch << 10) + (l << 4)) =
        (u32x4){pkf16(v0.x, v0.y), pkf16(v0.z, v0.w),
                pkf16(v1.x, v1.y), pkf16(v1.z, v1.w)};
  }
  __syncthreads();   // the only block barrier

  float csqv[8];
#pragma unroll
  for (int ct = 0; ct < 8; ++ct) csqv[ct] = csqnp[(ct << 4) + l15];

  const int nwaves = gridDim.x << 3;
  for (int t = (blockIdx.x << 3) + w; t < ntiles; t += nwaves) {
    const int row0 = t << 4;

    // ---- z A-frags direct from global + fp32 zsq.
    f16x8 az[8];
    float zs = 0.f;
    const float* zr = z + (size_t)(row0 + l15) * D_DIM + (g << 3);
#pragma unroll
    for (int k = 0; k < 8; ++k) {
      const float4 v0 = *(const float4*)(zr + (k << 5));
      const float4 v1 = *(const float4*)(zr + (k << 5) + 4);
      az[k] = __builtin_bit_cast(f16x8,
          (u32x4){pkf16(v0.x, v0.y), pkf16(v0.z, v0.w),
                  pkf16(v1.x, v1.y), pkf16(v1.z, v1.w)});
      zs += v0.x*v0.x + v0.y*v0.y + v0.z*v0.z + v0.w*v0.w
          + v1.x*v1.x + v1.y*v1.y + v1.z*v1.z + v1.w*v1.w;
    }
    zs += __shfl_xor(zs, 16);      // reduce over g: all lanes get zsq[row l15]
    zs += __shfl_xor(zs, 32);
    float zsqj[4];
#pragma unroll
    for (int j = 0; j < 4; ++j) zsqj[j] = __shfl(zs, (g << 2) + j);  // zsq[4g+j]

    // ---- MFMA: 8 k-steps x 8 cluster-tiles (independent acc chains).
    f32x4 acc[8];
#pragma unroll
    for (int ct = 0; ct < 8; ++ct) acc[ct] = (f32x4){0.f, 0.f, 0.f, 0.f};
#pragma unroll
    for (int k = 0; k < 8; ++k) {
#pragma unroll
      for (int ct = 0; ct < 8; ++ct) {
        const f16x8 b = *(const f16x8*)((char*)Bf + (((ct << 3) + k) << 10) + (l << 4));
        acc[ct] = __builtin_amdgcn_mfma_f32_16x16x32_f16(az[k], b, acc[ct], 0, 0, 0);
      }
    }

    // ---- epilogue in registers. acc[ct][j] = dot(z[row0+4g+j], cen[ct*16+l15]).
    unsigned km1[4], km2[4];
    float rinv[4];
#pragma unroll
    for (int j = 0; j < 4; ++j) {
      unsigned m1 = 0xFFFFFFFFu, m2 = 0xFFFFFFFFu;
      float sum = 0.f;
#pragma unroll
      for (int ct = 0; ct < 8; ++ct) {
        const float sq = fmaxf(fmaf(-2.0f, acc[ct][j], zsqj[j] + csqv[ct]), 0.0f);
        const unsigned u = (__float_as_uint(sq) & 0xFFFFFF80u) | (unsigned)((ct << 4) + l15);
        const unsigned mn = min(m1, u), mx = max(m1, u);
        m1 = mn; m2 = min(m2, mx);
        sum += __builtin_amdgcn_rcpf(
            1.0f + __builtin_amdgcn_sqrtf(__uint_as_float(u & 0xFFFFFF80u)));
      }
#pragma unroll
      for (int m = 1; m <= 8; m <<= 1) {   // butterfly over the 16-lane group
        const unsigned o1 = __shfl_xor(m1, m);
        const unsigned o2 = __shfl_xor(m2, m);
        sum += __shfl_xor(sum, m);
        const unsigned mn = min(m1, o1), mx = max(m1, o1);
        m1 = mn; m2 = min(mx, min(m2, o2));
      }
      km1[j] = m1; km2[j] = m2;
      rinv[j] = __builtin_amdgcn_rcpf(sum);
    }

    // ---- write s (from quantized sq, as r12) + c.
#pragma unroll
    for (int j = 0; j < 4; ++j) {
      float* srow = s_out + (size_t)(row0 + (g << 2) + j) * K_CL + l15;
#pragma unroll
      for (int ct = 0; ct < 8; ++ct) {
        const float sq = fmaxf(fmaf(-2.0f, acc[ct][j], zsqj[j] + csqv[ct]), 0.0f);
        const float sqq = __uint_as_float(__float_as_uint(sq) & 0xFFFFFF80u);
        srow[ct << 4] =
            __builtin_amdgcn_rcpf(1.0f + __builtin_amdgcn_sqrtf(sqq)) * rinv[j];
      }
      if (l15 == 0) c_out[row0 + (g << 2) + j] = (float)(km1[j] & 0x7Fu);
    }

    // ---- ambiguity mask (wave-uniform) + wave-local numpy-emulating refine.
    unsigned rowmask = 0;
#pragma unroll
    for (int j = 0; j < 4; ++j) {
      const float d1 = __uint_as_float(km1[j] & 0xFFFFFF80u);
      const float d2 = __uint_as_float(km2[j] & 0xFFFFFF80u);
      const unsigned long long b = __ballot(l15 == 0 && (d2 - d1) < MARGIN);
      rowmask |= (unsigned)(b & 1ull) << j;
      rowmask |= (unsigned)((b >> 16) & 1ull) << (4 + j);
      rowmask |= (unsigned)((b >> 32) & 1ull) << (8 + j);
      rowmask |= (unsigned)((b >> 48) & 1ull) << (12 + j);
    }

    while (rowmask) {
      const int r = __builtin_ctz(rowmask);
      rowmask &= rowmask - 1;
      const int grow = row0 + r;
      float* zrs = &zrow_s[w][0];
      float* sts = &stmp_s[w][0];
      *(float4*)(zrs + (l << 2)) =
          *(const float4*)(z + (size_t)grow * D_DIM + (l << 2));
      asm volatile("s_waitcnt lgkmcnt(0)" ::: "memory");
      // numpy-exact zsq (8-accumulator pattern, 8 lanes)
      float zblk = 0.f;
      if (l < 8) {
#pragma clang fp contract(off)
        float b0 = 0.f, b1 = 0.f;
        for (int b2 = 0; b2 < 2; ++b2) {
          const float* ab = zrs + (b2 << 7);
          float x = ab[l];
          float racc = x * x;
          for (int i = 1; i < 16; ++i) { x = ab[(i << 3) + l]; racc = racc + x * x; }
          racc = racc + __shfl_xor(racc, 1);
          racc = racc + __shfl_xor(racc, 2);
          racc = racc + __shfl_xor(racc, 4);
          if (b2 == 0) b0 = racc; else b1 = racc;
        }
        zblk = b0 + b1;
      }
      const float zsq_np = __shfl(zblk, 0);
      // fp64 dots: lane l -> clusters l and l+64, serial in-order over d
      // (reassoc slack ~1e-13 << 1.7e-4 fp32 s_tmp tie quantum).
      double d0 = 0.0, d1d = 0.0;
      const float* c0 = cen + (size_t)l * D_DIM;
      const float* c1 = cen + (size_t)(l + 64) * D_DIM;
      for (int d4 = 0; d4 < 64; ++d4) {
        const float4 zv = *(const float4*)(zrs + (d4 << 2));
        const float4 a0 = *(const float4*)(c0 + (d4 << 2));
        const float4 a1 = *(const float4*)(c1 + (d4 << 2));
        d0  += (double)zv.x * a0.x; d0  += (double)zv.y * a0.y;
        d0  += (double)zv.z * a0.z; d0  += (double)zv.w * a0.w;
        d1d += (double)zv.x * a1.x; d1d += (double)zv.y * a1.y;
        d1d += (double)zv.z * a1.z; d1d += (double)zv.w * a1.w;
      }
      float st0, st1;
      {
#pragma clang fp contract(off)
        const float dotf0 = (float)d0;
        const float sq0 = (zsq_np + csqnp[l]) - 2.0f * dotf0;
        st0 = 1.0f / (1.0f + sqrtf(fmaxf(sq0, 0.0f)));       // np pow -1 path
        const float dotf1 = (float)d1d;
        const float sq1 = (zsq_np + csqnp[l + 64]) - 2.0f * dotf1;
        st1 = 1.0f / (1.0f + sqrtf(fmaxf(sq1, 0.0f)));
      }
      sts[l] = st0;
      sts[l + 64] = st1;
      asm volatile("s_waitcnt lgkmcnt(0)" ::: "memory");
      // numpy-exact sum of stmp[128]
      float sblk = 0.f;
      if (l < 8) {
#pragma clang fp contract(off)
        float racc = sts[l];
        for (int i = 1; i < 16; ++i) racc = racc + sts[(i << 3) + l];
        racc = racc + __shfl_xor(racc, 1);
        racc = racc + __shfl_xor(racc, 2);
        racc = racc + __shfl_xor(racc, 4);
        sblk = racc;
      }
      const float ssum = __shfl(sblk, 0);
      const float s0 = st0 / ssum;   // IEEE div, like np
      const float s1 = st1 / ssum;
      unsigned long long k0 =
          ((unsigned long long)(0x7FFFFFFFu - __float_as_uint(s0)) << 32) | (unsigned)l;
      unsigned long long k1 =
          ((unsigned long long)(0x7FFFFFFFu - __float_as_uint(s1)) << 32) | (unsigned)(l + 64);
      unsigned long long kk = k0 < k1 ? k0 : k1;   // lower index wins ties
#pragma unroll
      for (int m = 1; m < 64; m <<= 1) {
        const unsigned long long o = __shfl_xor(kk, m);
        kk = o < kk ? o : kk;
      }
      if (l == 0) c_out[grow] = (float)(unsigned)(kk & 0x7Fu);
    }
  }
}

extern "C" void kernel_launch(void* const* d_in, const int* in_sizes, int n_in,
                              void* d_out, int out_size, void* d_ws, size_t ws_size,
                              hipStream_t stream) {
  const float* z   = (const float*)d_in[0];
  const float* cen = (const float*)d_in[1];
  const int M = in_sizes[0] / D_DIM;   // 131072
  float* s_out = (float*)d_out;
  float* c_out = s_out + (size_t)M * K_CL;
  const int ntiles = M / WR;           // 8192 wave-tiles
  const int nblk = 512;                // 4096 waves, 2 tiles each; 2 blocks/CU

  hipLaunchKernelGGL(k_main, dim3(nblk), dim3(512), 0, stream,
                     z, cen, s_out, c_out, ntiles);
}